// Round 6
// baseline (236.254 us; speedup 1.0000x reference)
//
#include <hip/hip_runtime.h>

// ROI bilinear pooling (tf.image.resize half-pixel centers), POOL=7.
// img: (1, 64, 64, 1024) fp32, NHWC. rois: (1, R, 4) int32 = [x, y, w, h].
// out: (1, R, 7, 7, 1024) fp32.
//
// R5 = R4 row kernel with ONE change: occupancy. Process the 7 cells in two
// batches (4+3 taps in flight instead of 28) and cap VGPRs via
// __launch_bounds__(256,4) -> ~4-5 waves/SIMD instead of ~3. Clean A/B on
// latency-hiding TLP; loads/stores/swizzle/math identical to R4.

#define POOLSZ 7
#define IMG_H 64
#define IMG_W 64
#define IMG_C 1024
#define NUM_XCD 8

typedef float v4f __attribute__((ext_vector_type(4)));

__global__ __launch_bounds__(256, 4) void roi_pool_row_kernel(
    const float* __restrict__ img,
    const int* __restrict__ rois,
    float* __restrict__ out,
    int roisPerXcd) {            // R/8 when R%8==0, else 0 (identity mapping)
    int r, py;
    if (roisPerXcd > 0) {
        // xcd = blockIdx % 8; chunk ROIs per XCD for L2 locality.
        const int xcd   = blockIdx.x & (NUM_XCD - 1);
        const int local = blockIdx.x >> 3;           // 0 .. R/8*7-1
        r  = xcd * roisPerXcd + local / POOLSZ;
        py = local % POOLSZ;
    } else {
        r  = blockIdx.x / POOLSZ;
        py = blockIdx.x % POOLSZ;
    }

    const int4 roi = ((const int4*)rois)[r];
    const int rx = roi.x, ry = roi.y, rw = roi.z, rh = roi.w;

    // y coords: src = (py+0.5)*h/7 - 0.5; lerp from unclipped floor (ref semantics)
    const float scy  = (float)rh * (1.0f / (float)POOLSZ);
    const float srcy = ((float)py + 0.5f) * scy - 0.5f;
    const float fy   = floorf(srcy);
    const float ty   = srcy - fy;
    const int   iy   = (int)fy;
    const int   y0   = ry + min(max(iy,     0), rh - 1);
    const int   y1   = ry + min(max(iy + 1, 0), rh - 1);

    // x coords for all 7 cells (cheap scalar-ish state: ints + floats)
    int   x0[POOLSZ], x1[POOLSZ];
    float tx[POOLSZ];
    const float scx = (float)rw * (1.0f / (float)POOLSZ);
#pragma unroll
    for (int px = 0; px < POOLSZ; ++px) {
        const float srcx = ((float)px + 0.5f) * scx - 0.5f;
        const float fx   = floorf(srcx);
        tx[px] = srcx - fx;
        const int ix = (int)fx;
        x0[px] = rx + min(max(ix,     0), rw - 1);
        x1[px] = rx + min(max(ix + 1, 0), rw - 1);
    }

    const int c4 = threadIdx.x;  // 0..255: float4 channel slice
    const v4f* row0 = (const v4f*)(img + (size_t)y0 * IMG_W * IMG_C) + c4;
    const v4f* row1 = (const v4f*)(img + (size_t)y1 * IMG_W * IMG_C) + c4;
    v4f* dst = (v4f*)out + ((size_t)r * POOLSZ + py) * POOLSZ * (IMG_C / 4) + c4;

    // Two batches: 4 cells then 3. <=16 v4f taps in flight -> fits 128 VGPRs.
#pragma unroll
    for (int batch = 0; batch < 2; ++batch) {
        const int off = batch ? 4 : 0;
        const int n   = batch ? 3 : 4;
        v4f a[4], b[4], c[4], d[4];
#pragma unroll
        for (int i = 0; i < 4; ++i) {
            if (i < n) {
                const int px = off + i;
                a[i] = row0[(size_t)x0[px] * (IMG_C / 4)];
                b[i] = row0[(size_t)x1[px] * (IMG_C / 4)];
                c[i] = row1[(size_t)x0[px] * (IMG_C / 4)];
                d[i] = row1[(size_t)x1[px] * (IMG_C / 4)];
            }
        }
#pragma unroll
        for (int i = 0; i < 4; ++i) {
            if (i < n) {
                const int px = off + i;
                const v4f top = a[i] + (b[i] - a[i]) * tx[px];
                const v4f bot = c[i] + (d[i] - c[i]) * tx[px];
                const v4f o   = top + (bot - top) * ty;
                dst[(size_t)px * (IMG_C / 4)] = o;
            }
        }
    }
}

extern "C" void kernel_launch(void* const* d_in, const int* in_sizes, int n_in,
                              void* d_out, int out_size, void* d_ws, size_t ws_size,
                              hipStream_t stream) {
    const float* img  = (const float*)d_in[0];
    const int*   rois = (const int*)d_in[1];
    float*       out  = (float*)d_out;
    const int R = in_sizes[1] / 4;                  // rois: (1, R, 4)
    const int n_rows = R * POOLSZ;                  // 1024*7 = 7168 blocks
    const int roisPerXcd = (R % NUM_XCD == 0) ? (R / NUM_XCD) : 0;
    roi_pool_row_kernel<<<n_rows, 256, 0, stream>>>(img, rois, out, roisPerXcd);
}